// Round 3
// baseline (972.447 us; speedup 1.0000x reference)
//
#include <hip/hip_runtime.h>

// GCN x2 layers x2 branches, N=50000 nodes, E=800000 edges, C=64.
// Both branches share edge structure/norms -> processed together in every
// kernel. dst-CSR built per launch (atomic histogram + 3-phase scan + fill).
// Aggregation = register gather (no f32 atomics). Layer-1 skip matmul fused
// into the agg kernel (shfl broadcast, W in LDS). Layer-2 agg fuses residual,
// Wf projection and graph pooling (1 scalar atomic per node).

// ---- degree histogram (doubles as CSR cursor after scanC rewrites it) ----
__global__ void deg_count_k(const int* __restrict__ dst, int nE, int* __restrict__ cnt) {
    int i = blockIdx.x * blockDim.x + threadIdx.x;
    if (i < nE) atomicAdd(&cnt[dst[i]], 1);
}

__global__ void dinv_k(const int* __restrict__ cnt, int n, float* __restrict__ dinv) {
    int i = blockIdx.x * blockDim.x + threadIdx.x;
    if (i < n) dinv[i] = 1.0f / sqrtf(1.0f + (float)cnt[i]);
}

// ---- 3-phase exclusive scan over cnt[0..n) ----
// A: per-block (1024 elems) exclusive scan into offs, block total to bsums.
__global__ __launch_bounds__(256) void scanA_k(const int* __restrict__ cnt, int n,
                                               int* __restrict__ offs, int* __restrict__ bsums) {
    int tid = threadIdx.x, lane = tid & 63, wid = tid >> 6;
    int base = blockIdx.x * 1024 + tid * 4;
    int v0 = (base + 0 < n) ? cnt[base + 0] : 0;
    int v1 = (base + 1 < n) ? cnt[base + 1] : 0;
    int v2 = (base + 2 < n) ? cnt[base + 2] : 0;
    int v3 = (base + 3 < n) ? cnt[base + 3] : 0;
    int lsum = v0 + v1 + v2 + v3;
    int s = lsum;
#pragma unroll
    for (int off = 1; off < 64; off <<= 1) {
        int t = __shfl_up(s, off);
        if (lane >= off) s += t;
    }
    __shared__ int wt[4];
    if (lane == 63) wt[wid] = s;
    __syncthreads();
    int woff = 0;
    for (int w = 0; w < wid; ++w) woff += wt[w];
    int excl = woff + s - lsum;
    if (base + 0 < n) offs[base + 0] = excl;
    if (base + 1 < n) offs[base + 1] = excl + v0;
    if (base + 2 < n) offs[base + 2] = excl + v0 + v1;
    if (base + 3 < n) offs[base + 3] = excl + v0 + v1 + v2;
    if (tid == 0) bsums[blockIdx.x] = wt[0] + wt[1] + wt[2] + wt[3];
}

// B: single-wave exclusive scan of block sums.
__global__ void scanB_k(const int* __restrict__ bsums, int nb, int* __restrict__ boffs) {
    int lane = threadIdx.x;
    int carry = 0;
    for (int base = 0; base < nb; base += 64) {
        int i = base + lane;
        int v = (i < nb) ? bsums[i] : 0;
        int s = v;
#pragma unroll
        for (int off = 1; off < 64; off <<= 1) {
            int t = __shfl_up(s, off);
            if (lane >= off) s += t;
        }
        if (i < nb) boffs[i] = carry + s - v;
        carry += __shfl(s, 63);
    }
}

// C: add block offsets; also writes the CSR fill cursor and offs[n].
__global__ __launch_bounds__(256) void scanC_k(int* __restrict__ offs,
                                               const int* __restrict__ boffs,
                                               int* __restrict__ cur, int n, int nE) {
    int boff = boffs[blockIdx.x];
    int base = blockIdx.x * 1024 + threadIdx.x * 4;
#pragma unroll
    for (int j = 0; j < 4; ++j) {
        int i = base + j;
        if (i < n) {
            int o = offs[i] + boff;
            offs[i] = o;
            cur[i] = o;
        }
    }
    if (blockIdx.x == 0 && threadIdx.x == 0) offs[n] = nE;
}

__global__ void fill_k(const int* __restrict__ src, const int* __restrict__ dst, int nE,
                       int* __restrict__ cur, int* __restrict__ elist) {
    int e = blockIdx.x * blockDim.x + threadIdx.x;
    if (e < nE) {
        int p = atomicAdd(&cur[dst[e]], 1);
        elist[p] = src[e];
    }
}

// Oa[row] = dinv[row]*(Xa[row]@Wa); Ob[row] = dinv[row]*(Xb[row]@Wb)
// One wave per row; W in LDS; x-row broadcast via shfl.
__global__ __launch_bounds__(256) void mm_pair_k(
    const float* __restrict__ Xa, const float* __restrict__ Xb,
    const float* __restrict__ Wa, const float* __restrict__ Wb,
    const float* __restrict__ dinv,
    float* __restrict__ Oa, float* __restrict__ Ob, int n) {
    __shared__ float wa[64][64];
    __shared__ float wb[64][64];
    for (int i = threadIdx.x; i < 64 * 64; i += blockDim.x) {
        wa[i >> 6][i & 63] = Wa[i];
        wb[i >> 6][i & 63] = Wb[i];
    }
    __syncthreads();
    const int lane = threadIdx.x & 63;
    const int row0 = blockIdx.x * 4 + (threadIdx.x >> 6);
    const int stride = gridDim.x * 4;
    for (int row = row0; row < n; row += stride) {
        float xv = Xa[row * 64 + lane];
        float xsv = Xb[row * 64 + lane];
        float acc1 = 0.f, acc2 = 0.f;
#pragma unroll
        for (int k = 0; k < 64; ++k) {
            float xb = __shfl(xv, k);
            float xsb = __shfl(xsv, k);
            acc1 = fmaf(xb, wa[k][lane], acc1);
            acc2 = fmaf(xsb, wb[k][lane], acc2);
        }
        float d = dinv[row];
        Oa[row * 64 + lane] = d * acc1;
        Ob[row * 64 + lane] = d * acc2;
    }
}

// Layer-1: gather-agg both branches + fused skip matmul (x@We etc).
// H1x[node] = relu(dinv*(sum A + self) + b) + relu(x@We + be)
__global__ __launch_bounds__(256) void agg_l1_k(
    const int* __restrict__ offs, const int* __restrict__ elist,
    const float* __restrict__ A1, const float* __restrict__ A2,
    const float* __restrict__ x, const float* __restrict__ xsc,
    const float* __restrict__ We, const float* __restrict__ Wes,
    const float* __restrict__ b1, const float* __restrict__ b1s,
    const float* __restrict__ be, const float* __restrict__ bes,
    const float* __restrict__ dinv,
    float* __restrict__ H11, float* __restrict__ H12, int n) {
    __shared__ float we[64][64];
    __shared__ float wes[64][64];
    for (int i = threadIdx.x; i < 64 * 64; i += blockDim.x) {
        we[i >> 6][i & 63] = We[i];
        wes[i >> 6][i & 63] = Wes[i];
    }
    __syncthreads();
    const int lane = threadIdx.x & 63;
    const float b1l = b1[lane], b1sl = b1s[lane], bel = be[lane], besl = bes[lane];
    const int node0 = blockIdx.x * 4 + (threadIdx.x >> 6);
    const int stride = gridDim.x * 4;
    for (int node = node0; node < n; node += stride) {
        int e0 = offs[node], e1 = offs[node + 1];
        float acc1 = A1[node * 64 + lane];  // self-loop term
        float acc2 = A2[node * 64 + lane];
        int e = e0;
        for (; e + 3 < e1; e += 4) {
            int s0 = elist[e], s1 = elist[e + 1], s2 = elist[e + 2], s3 = elist[e + 3];
            acc1 += (A1[s0 * 64 + lane] + A1[s1 * 64 + lane]) +
                    (A1[s2 * 64 + lane] + A1[s3 * 64 + lane]);
            acc2 += (A2[s0 * 64 + lane] + A2[s1 * 64 + lane]) +
                    (A2[s2 * 64 + lane] + A2[s3 * 64 + lane]);
        }
        for (; e < e1; ++e) {
            int s = elist[e];
            acc1 += A1[s * 64 + lane];
            acc2 += A2[s * 64 + lane];
        }
        float d = dinv[node];
        float g1 = fmaxf(d * acc1 + b1l, 0.0f);
        float g2 = fmaxf(d * acc2 + b1sl, 0.0f);
        // fused skip matmul
        float xv = x[node * 64 + lane];
        float xsv = xsc[node * 64 + lane];
        float sk1 = 0.f, sk2 = 0.f;
#pragma unroll
        for (int k = 0; k < 64; ++k) {
            float xb = __shfl(xv, k);
            float xsb = __shfl(xsv, k);
            sk1 = fmaf(xb, we[k][lane], sk1);
            sk2 = fmaf(xsb, wes[k][lane], sk2);
        }
        H11[node * 64 + lane] = g1 + fmaxf(sk1 + bel, 0.0f);
        H12[node * 64 + lane] = g2 + fmaxf(sk2 + besl, 0.0f);
    }
}

// Layer-2 + pool: gather-agg both branches, residual, dot(Wf), pooled atomic.
__global__ __launch_bounds__(256) void agg_l2_pool_k(
    const int* __restrict__ offs, const int* __restrict__ elist,
    const float* __restrict__ A1, const float* __restrict__ A2,
    const float* __restrict__ H11, const float* __restrict__ H12,
    const float* __restrict__ b2, const float* __restrict__ b2s,
    const float* __restrict__ Wf, const float* __restrict__ dinv,
    const int* __restrict__ batch, float* __restrict__ gsum, int n) {
    const int lane = threadIdx.x & 63;
    const float b2l = b2[lane], b2sl = b2s[lane], wfl = Wf[lane];
    int node = blockIdx.x * 4 + (threadIdx.x >> 6);
    if (node >= n) return;
    int e0 = offs[node], e1 = offs[node + 1];
    float acc1 = A1[node * 64 + lane];
    float acc2 = A2[node * 64 + lane];
    int e = e0;
    for (; e + 3 < e1; e += 4) {
        int s0 = elist[e], s1 = elist[e + 1], s2 = elist[e + 2], s3 = elist[e + 3];
        acc1 += (A1[s0 * 64 + lane] + A1[s1 * 64 + lane]) +
                (A1[s2 * 64 + lane] + A1[s3 * 64 + lane]);
        acc2 += (A2[s0 * 64 + lane] + A2[s1 * 64 + lane]) +
                (A2[s2 * 64 + lane] + A2[s3 * 64 + lane]);
    }
    for (; e < e1; ++e) {
        int s = elist[e];
        acc1 += A1[s * 64 + lane];
        acc2 += A2[s * 64 + lane];
    }
    float d = dinv[node];
    float h2  = fmaxf(d * acc1 + b2l, 0.0f) + H11[node * 64 + lane];
    float hs2 = fmaxf(d * acc2 + b2sl, 0.0f) + H12[node * 64 + lane];
    float c = (h2 + hs2) * wfl;
#pragma unroll
    for (int off = 32; off > 0; off >>= 1) c += __shfl_down(c, off);
    if (lane == 0) atomicAdd(&gsum[batch[node]], c);
}

__device__ inline int lower_bound(const int* __restrict__ batch, int n, int g) {
    int lo = 0, hi = n;
    while (lo < hi) {
        int mid = (lo + hi) >> 1;
        if (batch[mid] < g) lo = mid + 1; else hi = mid;
    }
    return lo;
}

// out[g] = gsum[g]/cnt[g] + bf  (cnt from sorted batch via binary search)
__global__ void final_k(const float* __restrict__ gsum, const int* __restrict__ batch,
                        int n, const float* __restrict__ bf, float* __restrict__ out, int nG) {
    int g = threadIdx.x + blockIdx.x * blockDim.x;
    if (g < nG) {
        int start = lower_bound(batch, n, g);
        int end = lower_bound(batch, n, g + 1);
        float cnt = fmaxf((float)(end - start), 1.0f);
        out[g] = gsum[g] / cnt + bf[0];
    }
}

extern "C" void kernel_launch(void* const* d_in, const int* in_sizes, int n_in,
                              void* d_out, int out_size, void* d_ws, size_t ws_size,
                              hipStream_t stream) {
    const float* x    = (const float*)d_in[0];
    const float* x_SC = (const float*)d_in[1];
    const float* W1   = (const float*)d_in[2];
    const float* b1   = (const float*)d_in[3];
    const float* W2   = (const float*)d_in[4];
    const float* b2   = (const float*)d_in[5];
    const float* We   = (const float*)d_in[6];
    const float* be   = (const float*)d_in[7];
    const float* W1s  = (const float*)d_in[8];
    const float* b1s  = (const float*)d_in[9];
    const float* W2s  = (const float*)d_in[10];
    const float* b2s  = (const float*)d_in[11];
    const float* Wes  = (const float*)d_in[12];
    const float* bes  = (const float*)d_in[13];
    const float* Wf   = (const float*)d_in[14];
    const float* bf   = (const float*)d_in[15];
    const int* ei     = (const int*)d_in[16];
    const int* batch  = (const int*)d_in[17];

    const int nN = in_sizes[0] / 64;   // 50000
    const int nE = in_sizes[16] / 2;   // 800000
    const int nG = out_size;           // 64
    const int* esrc = ei;
    const int* edst = ei + nE;
    const int nb = (nN + 1023) / 1024; // scan blocks (49)

    // ---- workspace ----
    char* p = (char*)d_ws;
    int* cur    = (int*)p;   p += (size_t)nN * sizeof(int);
    int* offs   = (int*)p;   p += (size_t)(nN + 1) * sizeof(int);
    int* elist  = (int*)p;   p += (size_t)nE * sizeof(int);
    int* bsums  = (int*)p;   p += 1024 * sizeof(int);
    int* boffs  = (int*)p;   p += 1024 * sizeof(int);
    float* dinv = (float*)p; p += (size_t)nN * sizeof(float);
    float* gsum = (float*)p; p += 1024 * sizeof(float);
    float* A1   = (float*)p; p += (size_t)nN * 64 * sizeof(float);
    float* A2   = (float*)p; p += (size_t)nN * 64 * sizeof(float);
    float* H11  = (float*)p; p += (size_t)nN * 64 * sizeof(float);
    float* H12  = (float*)p; p += (size_t)nN * 64 * sizeof(float);

    const int thr = 256;
    const int gEdgeT = (nE + thr - 1) / thr;
    const int gNodeT = (nN + thr - 1) / thr;
    const int gNodeW = (nN + 3) / 4;     // 1 wave/node

    // ---- CSR build + dinv ----
    hipMemsetAsync(cur, 0, (size_t)nN * sizeof(int), stream);
    hipMemsetAsync(gsum, 0, (size_t)nG * sizeof(float), stream);
    deg_count_k<<<gEdgeT, thr, 0, stream>>>(edst, nE, cur);
    dinv_k<<<gNodeT, thr, 0, stream>>>(cur, nN, dinv);
    scanA_k<<<nb, thr, 0, stream>>>(cur, nN, offs, bsums);
    scanB_k<<<1, 64, 0, stream>>>(bsums, nb, boffs);
    scanC_k<<<nb, thr, 0, stream>>>(offs, boffs, cur, nN, nE);
    fill_k<<<gEdgeT, thr, 0, stream>>>(esrc, edst, nE, cur, elist);

    // ---- layer 1 (both branches) ----
    mm_pair_k<<<1024, thr, 0, stream>>>(x, x_SC, W1, W1s, dinv, A1, A2, nN);
    agg_l1_k<<<2048, thr, 0, stream>>>(offs, elist, A1, A2, x, x_SC, We, Wes,
                                       b1, b1s, be, bes, dinv, H11, H12, nN);

    // ---- layer 2 (both branches) + pooled projection ----
    mm_pair_k<<<1024, thr, 0, stream>>>(H11, H12, W2, W2s, dinv, A1, A2, nN);
    agg_l2_pool_k<<<gNodeW, thr, 0, stream>>>(offs, elist, A1, A2, H11, H12,
                                              b2, b2s, Wf, dinv, batch, gsum, nN);

    // ---- final ----
    final_k<<<1, 64, 0, stream>>>(gsum, batch, nN, bf, (float*)d_out, nG);
}

// Round 4
// 629.941 us; speedup vs baseline: 1.5437x; 1.5437x over previous
//
#include <hip/hip_runtime.h>
#include <hip/hip_fp16.h>

// GCN x2 layers x2 branches, N=50000, E=800000, C=64.
// Round-4 structure: per-branch register-gather aggregation (round-2 shape,
// empirically fast) over f16 tables (128 B/row = 1 cache line/edge),
// multi-block scan for CSR build, fused matmuls, atomic-free pooling.

// ---- degree histogram (doubles as CSR cursor after scanC rewrites it) ----
__global__ void deg_count_k(const int* __restrict__ dst, int nE, int* __restrict__ cnt) {
    int i = blockIdx.x * blockDim.x + threadIdx.x;
    if (i < nE) atomicAdd(&cnt[dst[i]], 1);
}

__global__ void dinv_k(const int* __restrict__ cnt, int n, float* __restrict__ dinv) {
    int i = blockIdx.x * blockDim.x + threadIdx.x;
    if (i < n) dinv[i] = 1.0f / sqrtf(1.0f + (float)cnt[i]);
}

// ---- 3-phase exclusive scan ----
__global__ __launch_bounds__(256) void scanA_k(const int* __restrict__ cnt, int n,
                                               int* __restrict__ offs, int* __restrict__ bsums) {
    int tid = threadIdx.x, lane = tid & 63, wid = tid >> 6;
    int base = blockIdx.x * 1024 + tid * 4;
    int v0 = (base + 0 < n) ? cnt[base + 0] : 0;
    int v1 = (base + 1 < n) ? cnt[base + 1] : 0;
    int v2 = (base + 2 < n) ? cnt[base + 2] : 0;
    int v3 = (base + 3 < n) ? cnt[base + 3] : 0;
    int lsum = v0 + v1 + v2 + v3;
    int s = lsum;
#pragma unroll
    for (int off = 1; off < 64; off <<= 1) {
        int t = __shfl_up(s, off);
        if (lane >= off) s += t;
    }
    __shared__ int wt[4];
    if (lane == 63) wt[wid] = s;
    __syncthreads();
    int woff = 0;
    for (int w = 0; w < wid; ++w) woff += wt[w];
    int excl = woff + s - lsum;
    if (base + 0 < n) offs[base + 0] = excl;
    if (base + 1 < n) offs[base + 1] = excl + v0;
    if (base + 2 < n) offs[base + 2] = excl + v0 + v1;
    if (base + 3 < n) offs[base + 3] = excl + v0 + v1 + v2;
    if (tid == 0) bsums[blockIdx.x] = wt[0] + wt[1] + wt[2] + wt[3];
}

__global__ void scanB_k(const int* __restrict__ bsums, int nb, int* __restrict__ boffs) {
    int lane = threadIdx.x;
    int carry = 0;
    for (int base = 0; base < nb; base += 64) {
        int i = base + lane;
        int v = (i < nb) ? bsums[i] : 0;
        int s = v;
#pragma unroll
        for (int off = 1; off < 64; off <<= 1) {
            int t = __shfl_up(s, off);
            if (lane >= off) s += t;
        }
        if (i < nb) boffs[i] = carry + s - v;
        carry += __shfl(s, 63);
    }
}

__global__ __launch_bounds__(256) void scanC_k(int* __restrict__ offs,
                                               const int* __restrict__ boffs,
                                               int* __restrict__ cur, int n, int nE) {
    int boff = boffs[blockIdx.x];
    int base = blockIdx.x * 1024 + threadIdx.x * 4;
#pragma unroll
    for (int j = 0; j < 4; ++j) {
        int i = base + j;
        if (i < n) {
            int o = offs[i] + boff;
            offs[i] = o;
            cur[i] = o;
        }
    }
    if (blockIdx.x == 0 && threadIdx.x == 0) offs[n] = nE;
}

__global__ void fill_k(const int* __restrict__ src, const int* __restrict__ dst, int nE,
                       int* __restrict__ cur, int* __restrict__ elist) {
    int e = blockIdx.x * blockDim.x + threadIdx.x;
    if (e < nE) {
        int p = atomicAdd(&cur[dst[e]], 1);
        elist[p] = src[e];
    }
}

// ---- layer-1 matmuls, all four at once (W1,W1s,We,Wes in LDS = 64 KB) ----
// A1h = f16(dinv*(x@W1)); A2h = f16(dinv*(xsc@W1s)); S1 = f16(x@We); S2 = f16(xsc@Wes)
__global__ __launch_bounds__(256) void mm_quad_k(
    const float* __restrict__ X1, const float* __restrict__ X2,
    const float* __restrict__ W1, const float* __restrict__ W1s,
    const float* __restrict__ We, const float* __restrict__ Wes,
    const float* __restrict__ dinv,
    __half* __restrict__ A1h, __half* __restrict__ A2h,
    __half* __restrict__ S1, __half* __restrict__ S2, int n) {
    __shared__ float w1[64][64], w1s[64][64], we[64][64], wes[64][64];
    for (int i = threadIdx.x; i < 64 * 64; i += blockDim.x) {
        int r = i >> 6, c = i & 63;
        w1[r][c] = W1[i];
        w1s[r][c] = W1s[i];
        we[r][c] = We[i];
        wes[r][c] = Wes[i];
    }
    __syncthreads();
    const int lane = threadIdx.x & 63;
    const int row0 = blockIdx.x * 4 + (threadIdx.x >> 6);
    const int stride = gridDim.x * 4;
    for (int row = row0; row < n; row += stride) {
        float xv = X1[row * 64 + lane];
        float xsv = X2[row * 64 + lane];
        float a1 = 0.f, a2 = 0.f, s1 = 0.f, s2 = 0.f;
#pragma unroll
        for (int k = 0; k < 64; ++k) {
            float xb = __shfl(xv, k);
            float xsb = __shfl(xsv, k);
            a1 = fmaf(xb, w1[k][lane], a1);
            s1 = fmaf(xb, we[k][lane], s1);
            a2 = fmaf(xsb, w1s[k][lane], a2);
            s2 = fmaf(xsb, wes[k][lane], s2);
        }
        float d = dinv[row];
        A1h[row * 64 + lane] = __float2half(d * a1);
        A2h[row * 64 + lane] = __float2half(d * a2);
        S1[row * 64 + lane] = __float2half(s1);
        S2[row * 64 + lane] = __float2half(s2);
    }
}

// ---- layer-2 matmuls (pair) ----
__global__ __launch_bounds__(256) void mm_pair_k(
    const float* __restrict__ X1, const float* __restrict__ X2,
    const float* __restrict__ Wa, const float* __restrict__ Wb,
    const float* __restrict__ dinv,
    __half* __restrict__ O1, __half* __restrict__ O2, int n) {
    __shared__ float wa[64][64], wb[64][64];
    for (int i = threadIdx.x; i < 64 * 64; i += blockDim.x) {
        wa[i >> 6][i & 63] = Wa[i];
        wb[i >> 6][i & 63] = Wb[i];
    }
    __syncthreads();
    const int lane = threadIdx.x & 63;
    const int row0 = blockIdx.x * 4 + (threadIdx.x >> 6);
    const int stride = gridDim.x * 4;
    for (int row = row0; row < n; row += stride) {
        float xv = X1[row * 64 + lane];
        float xsv = X2[row * 64 + lane];
        float a1 = 0.f, a2 = 0.f;
#pragma unroll
        for (int k = 0; k < 64; ++k) {
            float xb = __shfl(xv, k);
            float xsb = __shfl(xsv, k);
            a1 = fmaf(xb, wa[k][lane], a1);
            a2 = fmaf(xsb, wb[k][lane], a2);
        }
        float d = dinv[row];
        O1[row * 64 + lane] = __float2half(d * a1);
        O2[row * 64 + lane] = __float2half(d * a2);
    }
}

// ---- layer-1 agg (per branch): gather f16 rows, epilogue with f16 skip ----
// H[node] = relu(dinv*(self + sum A[src]) + b) + relu(skip + bskip)   (f32 out)
__global__ __launch_bounds__(256) void agg1_k(
    const int* __restrict__ offs, const int* __restrict__ elist,
    const __half* __restrict__ Ah, const __half* __restrict__ skip,
    const float* __restrict__ b, const float* __restrict__ bskip,
    const float* __restrict__ dinv, float* __restrict__ H, int n) {
    int node = blockIdx.x * 4 + (threadIdx.x >> 6);
    int lane = threadIdx.x & 63;
    if (node >= n) return;
    int e0 = offs[node], e1 = offs[node + 1];
    float acc = __half2float(Ah[node * 64 + lane]);  // self-loop (pre-scaled)
    int e = e0;
    for (; e + 3 < e1; e += 4) {
        int s0 = elist[e], s1 = elist[e + 1], s2 = elist[e + 2], s3 = elist[e + 3];
        float v0 = __half2float(Ah[s0 * 64 + lane]);
        float v1 = __half2float(Ah[s1 * 64 + lane]);
        float v2 = __half2float(Ah[s2 * 64 + lane]);
        float v3 = __half2float(Ah[s3 * 64 + lane]);
        acc += (v0 + v1) + (v2 + v3);
    }
    for (; e < e1; ++e) acc += __half2float(Ah[elist[e] * 64 + lane]);
    float g = fmaxf(dinv[node] * acc + b[lane], 0.0f);
    float sk = __half2float(skip[node * 64 + lane]) + bskip[lane];
    H[node * 64 + lane] = g + fmaxf(sk, 0.0f);
}

// ---- layer-2 agg (per branch): gather f16 rows, residual f32, f16 out ----
__global__ __launch_bounds__(256) void agg2_k(
    const int* __restrict__ offs, const int* __restrict__ elist,
    const __half* __restrict__ Ah, const float* __restrict__ H1,
    const float* __restrict__ b, const float* __restrict__ dinv,
    __half* __restrict__ out, int n) {
    int node = blockIdx.x * 4 + (threadIdx.x >> 6);
    int lane = threadIdx.x & 63;
    if (node >= n) return;
    int e0 = offs[node], e1 = offs[node + 1];
    float acc = __half2float(Ah[node * 64 + lane]);
    int e = e0;
    for (; e + 3 < e1; e += 4) {
        int s0 = elist[e], s1 = elist[e + 1], s2 = elist[e + 2], s3 = elist[e + 3];
        float v0 = __half2float(Ah[s0 * 64 + lane]);
        float v1 = __half2float(Ah[s1 * 64 + lane]);
        float v2 = __half2float(Ah[s2 * 64 + lane]);
        float v3 = __half2float(Ah[s3 * 64 + lane]);
        acc += (v0 + v1) + (v2 + v3);
    }
    for (; e < e1; ++e) acc += __half2float(Ah[elist[e] * 64 + lane]);
    float g = fmaxf(dinv[node] * acc + b[lane], 0.0f);
    out[node * 64 + lane] = __float2half(g + H1[node * 64 + lane]);
}

// ---- pool + final projection, atomic-free (batch sorted) ----
__device__ inline int lower_bound(const int* __restrict__ batch, int n, int g) {
    int lo = 0, hi = n;
    while (lo < hi) {
        int mid = (lo + hi) >> 1;
        if (batch[mid] < g) lo = mid + 1; else hi = mid;
    }
    return lo;
}

__global__ __launch_bounds__(256) void pool_final_k(
    const __half* __restrict__ h2, const __half* __restrict__ hs2,
    const int* __restrict__ batch, int n,
    const float* __restrict__ Wf, const float* __restrict__ bf,
    float* __restrict__ out) {
    int g = blockIdx.x;
    int start = lower_bound(batch, n, g);
    int end = lower_bound(batch, n, g + 1);
    int lane = threadIdx.x & 63, wid = threadIdx.x >> 6;
    __shared__ float part[4][64];
    float acc = 0.f;
    for (int node = start + wid; node < end; node += 4)
        acc += __half2float(h2[node * 64 + lane]) + __half2float(hs2[node * 64 + lane]);
    part[wid][lane] = acc;
    __syncthreads();
    if (wid == 0) {
        float s = part[0][lane] + part[1][lane] + part[2][lane] + part[3][lane];
        float cnt = fmaxf((float)(end - start), 1.0f);
        s = (s / cnt) * Wf[lane];
#pragma unroll
        for (int off = 32; off > 0; off >>= 1) s += __shfl_down(s, off);
        if (lane == 0) out[g] = s + bf[0];
    }
}

extern "C" void kernel_launch(void* const* d_in, const int* in_sizes, int n_in,
                              void* d_out, int out_size, void* d_ws, size_t ws_size,
                              hipStream_t stream) {
    const float* x    = (const float*)d_in[0];
    const float* x_SC = (const float*)d_in[1];
    const float* W1   = (const float*)d_in[2];
    const float* b1   = (const float*)d_in[3];
    const float* W2   = (const float*)d_in[4];
    const float* b2   = (const float*)d_in[5];
    const float* We   = (const float*)d_in[6];
    const float* be   = (const float*)d_in[7];
    const float* W1s  = (const float*)d_in[8];
    const float* b1s  = (const float*)d_in[9];
    const float* W2s  = (const float*)d_in[10];
    const float* b2s  = (const float*)d_in[11];
    const float* Wes  = (const float*)d_in[12];
    const float* bes  = (const float*)d_in[13];
    const float* Wf   = (const float*)d_in[14];
    const float* bf   = (const float*)d_in[15];
    const int* ei     = (const int*)d_in[16];
    const int* batch  = (const int*)d_in[17];

    const int nN = in_sizes[0] / 64;   // 50000
    const int nE = in_sizes[16] / 2;   // 800000
    const int nG = out_size;           // 64
    const int* esrc = ei;
    const int* edst = ei + nE;
    const int nb = (nN + 1023) / 1024;

    // ---- workspace (~55 MB) ----
    char* p = (char*)d_ws;
    int* cur    = (int*)p;    p += (size_t)nN * sizeof(int);
    int* offs   = (int*)p;    p += (size_t)(nN + 1) * sizeof(int);
    int* elist  = (int*)p;    p += (size_t)nE * sizeof(int);
    int* bsums  = (int*)p;    p += 1024 * sizeof(int);
    int* boffs  = (int*)p;    p += 1024 * sizeof(int);
    float* dinv = (float*)p;  p += (size_t)nN * sizeof(float);
    __half* A1h = (__half*)p; p += (size_t)nN * 64 * sizeof(__half);
    __half* A2h = (__half*)p; p += (size_t)nN * 64 * sizeof(__half);
    __half* S1  = (__half*)p; p += (size_t)nN * 64 * sizeof(__half);  // skip, later H2_1
    __half* S2  = (__half*)p; p += (size_t)nN * 64 * sizeof(__half);  // skip, later H2_2
    float* H11  = (float*)p;  p += (size_t)nN * 64 * sizeof(float);
    float* H12  = (float*)p;  p += (size_t)nN * 64 * sizeof(float);

    const int thr = 256;
    const int gEdgeT = (nE + thr - 1) / thr;
    const int gNodeT = (nN + thr - 1) / thr;
    const int gNodeW = (nN + 3) / 4;   // 1 wave/node

    // ---- CSR build + dinv ----
    hipMemsetAsync(cur, 0, (size_t)nN * sizeof(int), stream);
    deg_count_k<<<gEdgeT, thr, 0, stream>>>(edst, nE, cur);
    dinv_k<<<gNodeT, thr, 0, stream>>>(cur, nN, dinv);
    scanA_k<<<nb, thr, 0, stream>>>(cur, nN, offs, bsums);
    scanB_k<<<1, 64, 0, stream>>>(bsums, nb, boffs);
    scanC_k<<<nb, thr, 0, stream>>>(offs, boffs, cur, nN, nE);
    fill_k<<<gEdgeT, thr, 0, stream>>>(esrc, edst, nE, cur, elist);

    // ---- layer 1 ----
    mm_quad_k<<<512, thr, 0, stream>>>(x, x_SC, W1, W1s, We, Wes, dinv,
                                       A1h, A2h, S1, S2, nN);
    agg1_k<<<gNodeW, thr, 0, stream>>>(offs, elist, A1h, S1, b1, be, dinv, H11, nN);
    agg1_k<<<gNodeW, thr, 0, stream>>>(offs, elist, A2h, S2, b1s, bes, dinv, H12, nN);

    // ---- layer 2 ----
    mm_pair_k<<<1024, thr, 0, stream>>>(H11, H12, W2, W2s, dinv, A1h, A2h, nN);
    agg2_k<<<gNodeW, thr, 0, stream>>>(offs, elist, A1h, H11, b2, dinv, S1, nN);
    agg2_k<<<gNodeW, thr, 0, stream>>>(offs, elist, A2h, H12, b2s, dinv, S2, nN);

    // ---- pool + final ----
    pool_final_k<<<nG, thr, 0, stream>>>(S1, S2, batch, nN, Wf, bf, (float*)d_out);
}

// Round 6
// 436.609 us; speedup vs baseline: 2.2273x; 1.4428x over previous
//
#include <hip/hip_runtime.h>

// GCN x2 layers x2 branches, N=50000, E=800000, C=64.
// Structure: per-branch f16 gather tables (128 B/row = 1 cache line/edge),
// MFMA (16x16x32 f16) matmuls with W in VGPR fragments, multi-block scan CSR
// build, atomic-free pooling.

typedef _Float16 f16;
typedef _Float16 f16x8 __attribute__((ext_vector_type(8)));
typedef float f32x4 __attribute__((ext_vector_type(4)));

// ---- degree histogram (doubles as CSR cursor after scanC rewrites it) ----
__global__ void deg_count_k(const int* __restrict__ dst, int nE, int* __restrict__ cnt) {
    int i = blockIdx.x * blockDim.x + threadIdx.x;
    if (i < nE) atomicAdd(&cnt[dst[i]], 1);
}

__global__ void dinv_k(const int* __restrict__ cnt, int n, float* __restrict__ dinv) {
    int i = blockIdx.x * blockDim.x + threadIdx.x;
    if (i < n) dinv[i] = 1.0f / sqrtf(1.0f + (float)cnt[i]);
}

// ---- 3-phase exclusive scan ----
__global__ __launch_bounds__(256) void scanA_k(const int* __restrict__ cnt, int n,
                                               int* __restrict__ offs, int* __restrict__ bsums) {
    int tid = threadIdx.x, lane = tid & 63, wid = tid >> 6;
    int base = blockIdx.x * 1024 + tid * 4;
    int v0 = (base + 0 < n) ? cnt[base + 0] : 0;
    int v1 = (base + 1 < n) ? cnt[base + 1] : 0;
    int v2 = (base + 2 < n) ? cnt[base + 2] : 0;
    int v3 = (base + 3 < n) ? cnt[base + 3] : 0;
    int lsum = v0 + v1 + v2 + v3;
    int s = lsum;
#pragma unroll
    for (int off = 1; off < 64; off <<= 1) {
        int t = __shfl_up(s, off);
        if (lane >= off) s += t;
    }
    __shared__ int wt[4];
    if (lane == 63) wt[wid] = s;
    __syncthreads();
    int woff = 0;
    for (int w = 0; w < wid; ++w) woff += wt[w];
    int excl = woff + s - lsum;
    if (base + 0 < n) offs[base + 0] = excl;
    if (base + 1 < n) offs[base + 1] = excl + v0;
    if (base + 2 < n) offs[base + 2] = excl + v0 + v1;
    if (base + 3 < n) offs[base + 3] = excl + v0 + v1 + v2;
    if (tid == 0) bsums[blockIdx.x] = wt[0] + wt[1] + wt[2] + wt[3];
}

__global__ void scanB_k(const int* __restrict__ bsums, int nb, int* __restrict__ boffs) {
    int lane = threadIdx.x;
    int carry = 0;
    for (int base = 0; base < nb; base += 64) {
        int i = base + lane;
        int v = (i < nb) ? bsums[i] : 0;
        int s = v;
#pragma unroll
        for (int off = 1; off < 64; off <<= 1) {
            int t = __shfl_up(s, off);
            if (lane >= off) s += t;
        }
        if (i < nb) boffs[i] = carry + s - v;
        carry += __shfl(s, 63);
    }
}

__global__ __launch_bounds__(256) void scanC_k(int* __restrict__ offs,
                                               const int* __restrict__ boffs,
                                               int* __restrict__ cur, int n, int nE) {
    int boff = boffs[blockIdx.x];
    int base = blockIdx.x * 1024 + threadIdx.x * 4;
#pragma unroll
    for (int j = 0; j < 4; ++j) {
        int i = base + j;
        if (i < n) {
            int o = offs[i] + boff;
            offs[i] = o;
            cur[i] = o;
        }
    }
    if (blockIdx.x == 0 && threadIdx.x == 0) offs[n] = nE;
}

__global__ void fill_k(const int* __restrict__ src, const int* __restrict__ dst, int nE,
                       int* __restrict__ cur, int* __restrict__ elist) {
    int e = blockIdx.x * blockDim.x + threadIdx.x;
    if (e < nE) {
        int p = atomicAdd(&cur[dst[e]], 1);
        elist[p] = src[e];
    }
}

// ---- MFMA matmul: per branch (blockIdx.y), Oa = f16(dinv*(X@Wa)),
//      and (NW==2) Oc = f16(X@Wc). One wave = 16-row x 64-col slab.
// 16x16x32 f16 layouts: A[row=l&15][k=(l>>4)*8+j]; B[k=(l>>4)*8+j][col=l&15];
// D[row=(l>>4)*4+j][col=l&15]  (m89-verified C/D mapping).
template <int NW>
__global__ __launch_bounds__(256) void mm_mfma_k(
    const float* __restrict__ X1, const float* __restrict__ X2,
    const float* __restrict__ Wa1, const float* __restrict__ Wa2,
    const float* __restrict__ Wc1, const float* __restrict__ Wc2,
    const float* __restrict__ dinv,
    f16* __restrict__ Oa1, f16* __restrict__ Oa2,
    f16* __restrict__ Oc1, f16* __restrict__ Oc2, int n) {
    const int branch = blockIdx.y;
    const float* X  = branch ? X2 : X1;
    const float* Wa = branch ? Wa2 : Wa1;
    const float* Wc = branch ? Wc2 : Wc1;
    f16* Oa = branch ? Oa2 : Oa1;
    f16* Oc = branch ? Oc2 : Oc1;

    const int lane = threadIdx.x & 63;
    const int col = lane & 15;       // B/D column within 16-col tile
    const int kgrp = lane >> 4;      // 0..3

    // W fragments in VGPRs: [col-tile][k-half]
    f16x8 wa[4][2], wc[4][2];
#pragma unroll
    for (int ct = 0; ct < 4; ++ct)
#pragma unroll
        for (int kk = 0; kk < 2; ++kk) {
#pragma unroll
            for (int j = 0; j < 8; ++j) {
                int widx = (kk * 32 + kgrp * 8 + j) * 64 + ct * 16 + col;
                wa[ct][kk][j] = (f16)Wa[widx];
                if (NW == 2) wc[ct][kk][j] = (f16)Wc[widx];
            }
        }

    const int wid = blockIdx.x * 4 + (threadIdx.x >> 6);
    const int nwaves = gridDim.x * 4;
    const int ntiles = (n + 15) >> 4;
    for (int t = wid; t < ntiles; t += nwaves) {
        // A fragments: lane reads row (t*16 + l&15), k-chunk (kgrp*8 .. +7)
        int arow = t * 16 + col;
        if (arow >= n) arow = n - 1;
        f16x8 af[2];
#pragma unroll
        for (int kk = 0; kk < 2; ++kk) {
            const float4* px = (const float4*)(X + (size_t)arow * 64 + kk * 32 + kgrp * 8);
            float4 u0 = px[0], u1 = px[1];
            af[kk][0] = (f16)u0.x; af[kk][1] = (f16)u0.y;
            af[kk][2] = (f16)u0.z; af[kk][3] = (f16)u0.w;
            af[kk][4] = (f16)u1.x; af[kk][5] = (f16)u1.y;
            af[kk][6] = (f16)u1.z; af[kk][7] = (f16)u1.w;
        }
        f32x4 acca[4], accc[4];
#pragma unroll
        for (int ct = 0; ct < 4; ++ct) {
            acca[ct] = (f32x4)(0.0f);
            if (NW == 2) accc[ct] = (f32x4)(0.0f);
        }
#pragma unroll
        for (int ct = 0; ct < 4; ++ct)
#pragma unroll
            for (int kk = 0; kk < 2; ++kk) {
                acca[ct] = __builtin_amdgcn_mfma_f32_16x16x32_f16(af[kk], wa[ct][kk], acca[ct], 0, 0, 0);
                if (NW == 2)
                    accc[ct] = __builtin_amdgcn_mfma_f32_16x16x32_f16(af[kk], wc[ct][kk], accc[ct], 0, 0, 0);
            }
        // epilogue: rows t*16 + kgrp*4 + j
        int rbase = t * 16 + kgrp * 4;
#pragma unroll
        for (int j = 0; j < 4; ++j) {
            int row = rbase + j;
            if (row < n) {
                float d = dinv[row];
#pragma unroll
                for (int ct = 0; ct < 4; ++ct) {
                    Oa[(size_t)row * 64 + ct * 16 + col] = (f16)(d * acca[ct][j]);
                    if (NW == 2)
                        Oc[(size_t)row * 64 + ct * 16 + col] = (f16)(accc[ct][j]);
                }
            }
        }
    }
}

// ---- layer-1 agg (per branch): gather f16 rows; epilogue with f16 skip ----
__global__ __launch_bounds__(256) void agg1_k(
    const int* __restrict__ offs, const int* __restrict__ elist,
    const f16* __restrict__ Ah, const f16* __restrict__ skip,
    const float* __restrict__ b, const float* __restrict__ bskip,
    const float* __restrict__ dinv, float* __restrict__ H, int n) {
    int node = blockIdx.x * 4 + (threadIdx.x >> 6);
    int lane = threadIdx.x & 63;
    if (node >= n) return;
    int e0 = offs[node], e1 = offs[node + 1];
    float acc = (float)Ah[(size_t)node * 64 + lane];  // self-loop (pre-scaled)
    int e = e0;
    for (; e + 7 < e1; e += 8) {
        int s0 = elist[e], s1 = elist[e + 1], s2 = elist[e + 2], s3 = elist[e + 3];
        int s4 = elist[e + 4], s5 = elist[e + 5], s6 = elist[e + 6], s7 = elist[e + 7];
        float v0 = (float)Ah[(size_t)s0 * 64 + lane];
        float v1 = (float)Ah[(size_t)s1 * 64 + lane];
        float v2 = (float)Ah[(size_t)s2 * 64 + lane];
        float v3 = (float)Ah[(size_t)s3 * 64 + lane];
        float v4 = (float)Ah[(size_t)s4 * 64 + lane];
        float v5 = (float)Ah[(size_t)s5 * 64 + lane];
        float v6 = (float)Ah[(size_t)s6 * 64 + lane];
        float v7 = (float)Ah[(size_t)s7 * 64 + lane];
        acc += ((v0 + v1) + (v2 + v3)) + ((v4 + v5) + (v6 + v7));
    }
    for (; e < e1; ++e) acc += (float)Ah[(size_t)elist[e] * 64 + lane];
    float g = fmaxf(dinv[node] * acc + b[lane], 0.0f);
    float sk = (float)skip[(size_t)node * 64 + lane] + bskip[lane];
    H[(size_t)node * 64 + lane] = g + fmaxf(sk, 0.0f);
}

// ---- layer-2 agg (per branch): gather f16 rows, residual f32, f16 out ----
__global__ __launch_bounds__(256) void agg2_k(
    const int* __restrict__ offs, const int* __restrict__ elist,
    const f16* __restrict__ Ah, const float* __restrict__ H1,
    const float* __restrict__ b, const float* __restrict__ dinv,
    f16* __restrict__ out, int n) {
    int node = blockIdx.x * 4 + (threadIdx.x >> 6);
    int lane = threadIdx.x & 63;
    if (node >= n) return;
    int e0 = offs[node], e1 = offs[node + 1];
    float acc = (float)Ah[(size_t)node * 64 + lane];
    int e = e0;
    for (; e + 7 < e1; e += 8) {
        int s0 = elist[e], s1 = elist[e + 1], s2 = elist[e + 2], s3 = elist[e + 3];
        int s4 = elist[e + 4], s5 = elist[e + 5], s6 = elist[e + 6], s7 = elist[e + 7];
        float v0 = (float)Ah[(size_t)s0 * 64 + lane];
        float v1 = (float)Ah[(size_t)s1 * 64 + lane];
        float v2 = (float)Ah[(size_t)s2 * 64 + lane];
        float v3 = (float)Ah[(size_t)s3 * 64 + lane];
        float v4 = (float)Ah[(size_t)s4 * 64 + lane];
        float v5 = (float)Ah[(size_t)s5 * 64 + lane];
        float v6 = (float)Ah[(size_t)s6 * 64 + lane];
        float v7 = (float)Ah[(size_t)s7 * 64 + lane];
        acc += ((v0 + v1) + (v2 + v3)) + ((v4 + v5) + (v6 + v7));
    }
    for (; e < e1; ++e) acc += (float)Ah[(size_t)elist[e] * 64 + lane];
    float g = fmaxf(dinv[node] * acc + b[lane], 0.0f);
    out[(size_t)node * 64 + lane] = (f16)(g + H1[(size_t)node * 64 + lane]);
}

// ---- pool + final projection, atomic-free (batch sorted) ----
__device__ inline int lower_bound(const int* __restrict__ batch, int n, int g) {
    int lo = 0, hi = n;
    while (lo < hi) {
        int mid = (lo + hi) >> 1;
        if (batch[mid] < g) lo = mid + 1; else hi = mid;
    }
    return lo;
}

__global__ __launch_bounds__(256) void pool_final_k(
    const f16* __restrict__ h2, const f16* __restrict__ hs2,
    const int* __restrict__ batch, int n,
    const float* __restrict__ Wf, const float* __restrict__ bf,
    float* __restrict__ out) {
    int g = blockIdx.x;
    int start = lower_bound(batch, n, g);
    int end = lower_bound(batch, n, g + 1);
    int lane = threadIdx.x & 63, wid = threadIdx.x >> 6;
    __shared__ float part[4][64];
    float acc = 0.f;
    for (int node = start + wid; node < end; node += 4)
        acc += (float)h2[(size_t)node * 64 + lane] + (float)hs2[(size_t)node * 64 + lane];
    part[wid][lane] = acc;
    __syncthreads();
    if (wid == 0) {
        float s = part[0][lane] + part[1][lane] + part[2][lane] + part[3][lane];
        float cnt = fmaxf((float)(end - start), 1.0f);
        s = (s / cnt) * Wf[lane];
#pragma unroll
        for (int off = 32; off > 0; off >>= 1) s += __shfl_down(s, off);
        if (lane == 0) out[g] = s + bf[0];
    }
}

extern "C" void kernel_launch(void* const* d_in, const int* in_sizes, int n_in,
                              void* d_out, int out_size, void* d_ws, size_t ws_size,
                              hipStream_t stream) {
    const float* x    = (const float*)d_in[0];
    const float* x_SC = (const float*)d_in[1];
    const float* W1   = (const float*)d_in[2];
    const float* b1   = (const float*)d_in[3];
    const float* W2   = (const float*)d_in[4];
    const float* b2   = (const float*)d_in[5];
    const float* We   = (const float*)d_in[6];
    const float* be   = (const float*)d_in[7];
    const float* W1s  = (const float*)d_in[8];
    const float* b1s  = (const float*)d_in[9];
    const float* W2s  = (const float*)d_in[10];
    const float* b2s  = (const float*)d_in[11];
    const float* Wes  = (const float*)d_in[12];
    const float* bes  = (const float*)d_in[13];
    const float* Wf   = (const float*)d_in[14];
    const float* bf   = (const float*)d_in[15];
    const int* ei     = (const int*)d_in[16];
    const int* batch  = (const int*)d_in[17];

    const int nN = in_sizes[0] / 64;   // 50000
    const int nE = in_sizes[16] / 2;   // 800000
    const int nG = out_size;           // 64
    const int* esrc = ei;
    const int* edst = ei + nE;
    const int nb = (nN + 1023) / 1024;

    // ---- workspace ----
    char* p = (char*)d_ws;
    int* cur    = (int*)p;  p += (size_t)nN * sizeof(int);
    int* offs   = (int*)p;  p += (size_t)(nN + 1) * sizeof(int);
    int* elist  = (int*)p;  p += (size_t)nE * sizeof(int);
    int* bsums  = (int*)p;  p += 1024 * sizeof(int);
    int* boffs  = (int*)p;  p += 1024 * sizeof(int);
    float* dinv = (float*)p; p += (size_t)nN * sizeof(float);
    f16* A1h = (f16*)p;     p += (size_t)nN * 64 * sizeof(f16);
    f16* A2h = (f16*)p;     p += (size_t)nN * 64 * sizeof(f16);
    f16* S1  = (f16*)p;     p += (size_t)nN * 64 * sizeof(f16);  // skip, later H2_1
    f16* S2  = (f16*)p;     p += (size_t)nN * 64 * sizeof(f16);  // skip, later H2_2
    float* H11 = (float*)p; p += (size_t)nN * 64 * sizeof(float);
    float* H12 = (float*)p; p += (size_t)nN * 64 * sizeof(float);

    const int thr = 256;
    const int gEdgeT = (nE + thr - 1) / thr;
    const int gNodeT = (nN + thr - 1) / thr;
    const int gNodeW = (nN + 3) / 4;   // 1 wave/node

    // ---- CSR build + dinv ----
    hipMemsetAsync(cur, 0, (size_t)nN * sizeof(int), stream);
    deg_count_k<<<gEdgeT, thr, 0, stream>>>(edst, nE, cur);
    dinv_k<<<gNodeT, thr, 0, stream>>>(cur, nN, dinv);
    scanA_k<<<nb, thr, 0, stream>>>(cur, nN, offs, bsums);
    scanB_k<<<1, 64, 0, stream>>>(bsums, nb, boffs);
    scanC_k<<<nb, thr, 0, stream>>>(offs, boffs, cur, nN, nE);
    fill_k<<<gEdgeT, thr, 0, stream>>>(esrc, edst, nE, cur, elist);

    // ---- layer 1: A1h=f16(d*(x@W1)), A2h=f16(d*(xsc@W1s)), S1=x@We, S2=xsc@Wes
    mm_mfma_k<2><<<dim3(256, 2), thr, 0, stream>>>(
        x, x_SC, W1, W1s, We, Wes, dinv, A1h, A2h, S1, S2, nN);
    agg1_k<<<gNodeW, thr, 0, stream>>>(offs, elist, A1h, S1, b1, be, dinv, H11, nN);
    agg1_k<<<gNodeW, thr, 0, stream>>>(offs, elist, A2h, S2, b1s, bes, dinv, H12, nN);

    // ---- layer 2 ----
    mm_mfma_k<1><<<dim3(256, 2), thr, 0, stream>>>(
        H11, H12, W2, W2s, nullptr, nullptr, dinv, A1h, A2h, nullptr, nullptr, nN);
    agg2_k<<<gNodeW, thr, 0, stream>>>(offs, elist, A1h, H11, b2, dinv, S1, nN);
    agg2_k<<<gNodeW, thr, 0, stream>>>(offs, elist, A2h, H12, b2s, dinv, S2, nN);

    // ---- pool + final ----
    pool_final_k<<<nG, thr, 0, stream>>>(S1, S2, batch, nN, Wf, bf, (float*)d_out);
}

// Round 7
// 367.757 us; speedup vs baseline: 2.6443x; 1.1872x over previous
//
#include <hip/hip_runtime.h>
#include <stdint.h>

// GCN x2 layers x2 branches, N=50000, E=800000, C=64.
// f16 gather tables (128 B/row), MFMA 16x16x32 f16 matmuls (W in VGPRs),
// multi-block scan CSR build, Wf-dot fused into layer-2 agg, tiny pool reduce.

typedef _Float16 f16;
typedef _Float16 f16x8 __attribute__((ext_vector_type(8)));
typedef float f32x4 __attribute__((ext_vector_type(4)));

// ---- degree histogram (doubles as CSR cursor after scanC rewrites it) ----
__global__ void deg_count_k(const int* __restrict__ dst, int nE, int* __restrict__ cnt) {
    int i = blockIdx.x * blockDim.x + threadIdx.x;
    if (i < nE) atomicAdd(&cnt[dst[i]], 1);
}

__global__ void dinv_k(const int* __restrict__ cnt, int n, float* __restrict__ dinv) {
    int i = blockIdx.x * blockDim.x + threadIdx.x;
    if (i < n) dinv[i] = 1.0f / sqrtf(1.0f + (float)cnt[i]);
}

// ---- 3-phase exclusive scan ----
__global__ __launch_bounds__(256) void scanA_k(const int* __restrict__ cnt, int n,
                                               int* __restrict__ offs, int* __restrict__ bsums) {
    int tid = threadIdx.x, lane = tid & 63, wid = tid >> 6;
    int base = blockIdx.x * 1024 + tid * 4;
    int v0 = (base + 0 < n) ? cnt[base + 0] : 0;
    int v1 = (base + 1 < n) ? cnt[base + 1] : 0;
    int v2 = (base + 2 < n) ? cnt[base + 2] : 0;
    int v3 = (base + 3 < n) ? cnt[base + 3] : 0;
    int lsum = v0 + v1 + v2 + v3;
    int s = lsum;
#pragma unroll
    for (int off = 1; off < 64; off <<= 1) {
        int t = __shfl_up(s, off);
        if (lane >= off) s += t;
    }
    __shared__ int wt[4];
    if (lane == 63) wt[wid] = s;
    __syncthreads();
    int woff = 0;
    for (int w = 0; w < wid; ++w) woff += wt[w];
    int excl = woff + s - lsum;
    if (base + 0 < n) offs[base + 0] = excl;
    if (base + 1 < n) offs[base + 1] = excl + v0;
    if (base + 2 < n) offs[base + 2] = excl + v0 + v1;
    if (base + 3 < n) offs[base + 3] = excl + v0 + v1 + v2;
    if (tid == 0) bsums[blockIdx.x] = wt[0] + wt[1] + wt[2] + wt[3];
}

__global__ void scanB_k(const int* __restrict__ bsums, int nb, int* __restrict__ boffs) {
    int lane = threadIdx.x;
    int carry = 0;
    for (int base = 0; base < nb; base += 64) {
        int i = base + lane;
        int v = (i < nb) ? bsums[i] : 0;
        int s = v;
#pragma unroll
        for (int off = 1; off < 64; off <<= 1) {
            int t = __shfl_up(s, off);
            if (lane >= off) s += t;
        }
        if (i < nb) boffs[i] = carry + s - v;
        carry += __shfl(s, 63);
    }
}

__global__ __launch_bounds__(256) void scanC_k(int* __restrict__ offs,
                                               const int* __restrict__ boffs,
                                               int* __restrict__ cur, int n, int nE) {
    int boff = boffs[blockIdx.x];
    int base = blockIdx.x * 1024 + threadIdx.x * 4;
#pragma unroll
    for (int j = 0; j < 4; ++j) {
        int i = base + j;
        if (i < n) {
            int o = offs[i] + boff;
            offs[i] = o;
            cur[i] = o;
        }
    }
    if (blockIdx.x == 0 && threadIdx.x == 0) offs[n] = nE;
}

__global__ void fill_k(const int* __restrict__ src, const int* __restrict__ dst, int nE,
                       int* __restrict__ cur, int* __restrict__ elist) {
    int e = blockIdx.x * blockDim.x + threadIdx.x;
    if (e < nE) {
        int p = atomicAdd(&cur[dst[e]], 1);
        elist[p] = src[e];
    }
}

// ---- MFMA matmul: per branch (blockIdx.y), Oa = f16(dinv*(X@Wa)),
//      and (NW==2) Oc = f16(X@Wc). One wave = 16-row x 64-col slab.
// 16x16x32 f16 layouts: A[row=l&15][k=(l>>4)*8+j]; B[k=(l>>4)*8+j][col=l&15];
// D[row=(l>>4)*4+j][col=l&15]  (m89-verified C/D mapping).
template <int NW, bool F16IN>
__global__ __launch_bounds__(256) void mm_mfma_k(
    const void* __restrict__ X1, const void* __restrict__ X2,
    const float* __restrict__ Wa1, const float* __restrict__ Wa2,
    const float* __restrict__ Wc1, const float* __restrict__ Wc2,
    const float* __restrict__ dinv,
    f16* __restrict__ Oa1, f16* __restrict__ Oa2,
    f16* __restrict__ Oc1, f16* __restrict__ Oc2, int n) {
    const int branch = blockIdx.y;
    const void* X   = branch ? X2 : X1;
    const float* Wa = branch ? Wa2 : Wa1;
    const float* Wc = branch ? Wc2 : Wc1;
    f16* Oa = branch ? Oa2 : Oa1;
    f16* Oc = branch ? Oc2 : Oc1;

    const int lane = threadIdx.x & 63;
    const int col = lane & 15;       // B/D column within 16-col tile
    const int kgrp = lane >> 4;      // 0..3

    // W fragments in VGPRs: [col-tile][k-half]
    f16x8 wa[4][2], wc[4][2];
#pragma unroll
    for (int ct = 0; ct < 4; ++ct)
#pragma unroll
        for (int kk = 0; kk < 2; ++kk) {
#pragma unroll
            for (int j = 0; j < 8; ++j) {
                int widx = (kk * 32 + kgrp * 8 + j) * 64 + ct * 16 + col;
                wa[ct][kk][j] = (f16)Wa[widx];
                if (NW == 2) wc[ct][kk][j] = (f16)Wc[widx];
            }
        }

    const int wid = blockIdx.x * 4 + (threadIdx.x >> 6);
    const int nwaves = gridDim.x * 4;
    const int ntiles = (n + 15) >> 4;
    for (int t = wid; t < ntiles; t += nwaves) {
        int arow = t * 16 + col;
        if (arow >= n) arow = n - 1;
        f16x8 af[2];
#pragma unroll
        for (int kk = 0; kk < 2; ++kk) {
            if (F16IN) {
                af[kk] = *(const f16x8*)((const f16*)X + (size_t)arow * 64 + kk * 32 + kgrp * 8);
            } else {
                const float4* px = (const float4*)((const float*)X + (size_t)arow * 64 + kk * 32 + kgrp * 8);
                float4 u0 = px[0], u1 = px[1];
                af[kk][0] = (f16)u0.x; af[kk][1] = (f16)u0.y;
                af[kk][2] = (f16)u0.z; af[kk][3] = (f16)u0.w;
                af[kk][4] = (f16)u1.x; af[kk][5] = (f16)u1.y;
                af[kk][6] = (f16)u1.z; af[kk][7] = (f16)u1.w;
            }
        }
        f32x4 acca[4], accc[4];
#pragma unroll
        for (int ct = 0; ct < 4; ++ct) {
            acca[ct] = (f32x4)(0.0f);
            if (NW == 2) accc[ct] = (f32x4)(0.0f);
        }
#pragma unroll
        for (int ct = 0; ct < 4; ++ct)
#pragma unroll
            for (int kk = 0; kk < 2; ++kk) {
                acca[ct] = __builtin_amdgcn_mfma_f32_16x16x32_f16(af[kk], wa[ct][kk], acca[ct], 0, 0, 0);
                if (NW == 2)
                    accc[ct] = __builtin_amdgcn_mfma_f32_16x16x32_f16(af[kk], wc[ct][kk], accc[ct], 0, 0, 0);
            }
        int rbase = t * 16 + kgrp * 4;
#pragma unroll
        for (int j = 0; j < 4; ++j) {
            int row = rbase + j;
            if (row < n) {
                float d = dinv[row];
#pragma unroll
                for (int ct = 0; ct < 4; ++ct) {
                    Oa[(size_t)row * 64 + ct * 16 + col] = (f16)(d * acca[ct][j]);
                    if (NW == 2)
                        Oc[(size_t)row * 64 + ct * 16 + col] = (f16)(accc[ct][j]);
                }
            }
        }
    }
}

// ---- layer-1 agg (per branch): gather f16 rows; f16 H out ----
// H[node] = relu(dinv*(self + sum A[src]) + b) + relu(skip + bskip)
__global__ __launch_bounds__(256) void agg1_k(
    const int* __restrict__ offs, const int* __restrict__ elist,
    const f16* __restrict__ Ah, const f16* __restrict__ skip,
    const float* __restrict__ b, const float* __restrict__ bskip,
    const float* __restrict__ dinv, f16* __restrict__ H, int n) {
    int node = blockIdx.x * 4 + (threadIdx.x >> 6);
    int lane = threadIdx.x & 63;
    if (node >= n) return;
    int e0 = offs[node], e1 = offs[node + 1];
    float acc = (float)Ah[(size_t)node * 64 + lane];  // self-loop (pre-scaled)
    int e = e0;
    for (; e + 7 < e1; e += 8) {
        int s0 = elist[e], s1 = elist[e + 1], s2 = elist[e + 2], s3 = elist[e + 3];
        int s4 = elist[e + 4], s5 = elist[e + 5], s6 = elist[e + 6], s7 = elist[e + 7];
        float v0 = (float)Ah[(size_t)s0 * 64 + lane];
        float v1 = (float)Ah[(size_t)s1 * 64 + lane];
        float v2 = (float)Ah[(size_t)s2 * 64 + lane];
        float v3 = (float)Ah[(size_t)s3 * 64 + lane];
        float v4 = (float)Ah[(size_t)s4 * 64 + lane];
        float v5 = (float)Ah[(size_t)s5 * 64 + lane];
        float v6 = (float)Ah[(size_t)s6 * 64 + lane];
        float v7 = (float)Ah[(size_t)s7 * 64 + lane];
        acc += ((v0 + v1) + (v2 + v3)) + ((v4 + v5) + (v6 + v7));
    }
    for (; e < e1; ++e) acc += (float)Ah[(size_t)elist[e] * 64 + lane];
    float g = fmaxf(dinv[node] * acc + b[lane], 0.0f);
    float sk = (float)skip[(size_t)node * 64 + lane] + bskip[lane];
    H[(size_t)node * 64 + lane] = (f16)(g + fmaxf(sk, 0.0f));
}

// ---- layer-2 agg + Wf dot (per branch): no h2 materialization ----
// dot[node] = sum_ch (relu(dinv*(self+sum A) + b) + H1) * Wf[ch]
__global__ __launch_bounds__(256) void agg2_dot_k(
    const int* __restrict__ offs, const int* __restrict__ elist,
    const f16* __restrict__ Ah, const f16* __restrict__ H1,
    const float* __restrict__ b, const float* __restrict__ dinv,
    const float* __restrict__ Wf, float* __restrict__ dot, int n) {
    int node = blockIdx.x * 4 + (threadIdx.x >> 6);
    int lane = threadIdx.x & 63;
    if (node >= n) return;
    int e0 = offs[node], e1 = offs[node + 1];
    float acc = (float)Ah[(size_t)node * 64 + lane];
    int e = e0;
    for (; e + 7 < e1; e += 8) {
        int s0 = elist[e], s1 = elist[e + 1], s2 = elist[e + 2], s3 = elist[e + 3];
        int s4 = elist[e + 4], s5 = elist[e + 5], s6 = elist[e + 6], s7 = elist[e + 7];
        float v0 = (float)Ah[(size_t)s0 * 64 + lane];
        float v1 = (float)Ah[(size_t)s1 * 64 + lane];
        float v2 = (float)Ah[(size_t)s2 * 64 + lane];
        float v3 = (float)Ah[(size_t)s3 * 64 + lane];
        float v4 = (float)Ah[(size_t)s4 * 64 + lane];
        float v5 = (float)Ah[(size_t)s5 * 64 + lane];
        float v6 = (float)Ah[(size_t)s6 * 64 + lane];
        float v7 = (float)Ah[(size_t)s7 * 64 + lane];
        acc += ((v0 + v1) + (v2 + v3)) + ((v4 + v5) + (v6 + v7));
    }
    for (; e < e1; ++e) acc += (float)Ah[(size_t)elist[e] * 64 + lane];
    float h2 = fmaxf(dinv[node] * acc + b[lane], 0.0f) + (float)H1[(size_t)node * 64 + lane];
    float c = h2 * Wf[lane];
#pragma unroll
    for (int off = 32; off > 0; off >>= 1) c += __shfl_down(c, off);
    if (lane == 0) dot[node] = c;
}

// ---- pool: one block per graph over per-node dots (batch sorted) ----
__device__ inline int lower_bound(const int* __restrict__ batch, int n, int g) {
    int lo = 0, hi = n;
    while (lo < hi) {
        int mid = (lo + hi) >> 1;
        if (batch[mid] < g) lo = mid + 1; else hi = mid;
    }
    return lo;
}

__global__ __launch_bounds__(256) void pool_reduce_k(
    const float* __restrict__ dot1, const float* __restrict__ dot2,
    const int* __restrict__ batch, int n,
    const float* __restrict__ bf, float* __restrict__ out) {
    int g = blockIdx.x;
    int start = lower_bound(batch, n, g);
    int end = lower_bound(batch, n, g + 1);
    int tid = threadIdx.x, lane = tid & 63, wid = tid >> 6;
    float acc = 0.f;
    for (int i = start + tid; i < end; i += blockDim.x) acc += dot1[i] + dot2[i];
#pragma unroll
    for (int off = 32; off > 0; off >>= 1) acc += __shfl_down(acc, off);
    __shared__ float part[4];
    if (lane == 0) part[wid] = acc;
    __syncthreads();
    if (tid == 0) {
        float s = part[0] + part[1] + part[2] + part[3];
        float cnt = fmaxf((float)(end - start), 1.0f);
        out[g] = s / cnt + bf[0];
    }
}

static inline char* alignp(char* p, uintptr_t a) {
    return (char*)(((uintptr_t)p + a - 1) & ~(a - 1));
}

extern "C" void kernel_launch(void* const* d_in, const int* in_sizes, int n_in,
                              void* d_out, int out_size, void* d_ws, size_t ws_size,
                              hipStream_t stream) {
    const float* x    = (const float*)d_in[0];
    const float* x_SC = (const float*)d_in[1];
    const float* W1   = (const float*)d_in[2];
    const float* b1   = (const float*)d_in[3];
    const float* W2   = (const float*)d_in[4];
    const float* b2   = (const float*)d_in[5];
    const float* We   = (const float*)d_in[6];
    const float* be   = (const float*)d_in[7];
    const float* W1s  = (const float*)d_in[8];
    const float* b1s  = (const float*)d_in[9];
    const float* W2s  = (const float*)d_in[10];
    const float* b2s  = (const float*)d_in[11];
    const float* Wes  = (const float*)d_in[12];
    const float* bes  = (const float*)d_in[13];
    const float* Wf   = (const float*)d_in[14];
    const float* bf   = (const float*)d_in[15];
    const int* ei     = (const int*)d_in[16];
    const int* batch  = (const int*)d_in[17];

    const int nN = in_sizes[0] / 64;   // 50000
    const int nE = in_sizes[16] / 2;   // 800000
    const int nG = out_size;           // 64
    const int* esrc = ei;
    const int* edst = ei + nE;
    const int nb = (nN + 1023) / 1024;

    // ---- workspace (64B-aligned chunks) ----
    char* p = (char*)d_ws;
    int* cur    = (int*)p;   p = alignp(p + (size_t)nN * sizeof(int), 64);
    int* offs   = (int*)p;   p = alignp(p + (size_t)(nN + 1) * sizeof(int), 64);
    int* elist  = (int*)p;   p = alignp(p + (size_t)nE * sizeof(int), 64);
    int* bsums  = (int*)p;   p = alignp(p + 1024 * sizeof(int), 64);
    int* boffs  = (int*)p;   p = alignp(p + 1024 * sizeof(int), 64);
    float* dinv = (float*)p; p = alignp(p + (size_t)nN * sizeof(float), 64);
    float* dot1 = (float*)p; p = alignp(p + (size_t)nN * sizeof(float), 64);
    float* dot2 = (float*)p; p = alignp(p + (size_t)nN * sizeof(float), 64);
    f16* A1h = (f16*)p;      p = alignp(p + (size_t)nN * 64 * sizeof(f16), 64);
    f16* A2h = (f16*)p;      p = alignp(p + (size_t)nN * 64 * sizeof(f16), 64);
    f16* S1  = (f16*)p;      p = alignp(p + (size_t)nN * 64 * sizeof(f16), 64);
    f16* S2  = (f16*)p;      p = alignp(p + (size_t)nN * 64 * sizeof(f16), 64);
    f16* H11 = (f16*)p;      p = alignp(p + (size_t)nN * 64 * sizeof(f16), 64);
    f16* H12 = (f16*)p;      p = alignp(p + (size_t)nN * 64 * sizeof(f16), 64);

    const int thr = 256;
    const int gEdgeT = (nE + thr - 1) / thr;
    const int gNodeT = (nN + thr - 1) / thr;
    const int gNodeW = (nN + 3) / 4;   // 1 wave/node

    // ---- CSR build + dinv ----
    hipMemsetAsync(cur, 0, (size_t)nN * sizeof(int), stream);
    deg_count_k<<<gEdgeT, thr, 0, stream>>>(edst, nE, cur);
    dinv_k<<<gNodeT, thr, 0, stream>>>(cur, nN, dinv);
    scanA_k<<<nb, thr, 0, stream>>>(cur, nN, offs, bsums);
    scanB_k<<<1, 64, 0, stream>>>(bsums, nb, boffs);
    scanC_k<<<nb, thr, 0, stream>>>(offs, boffs, cur, nN, nE);
    fill_k<<<gEdgeT, thr, 0, stream>>>(esrc, edst, nE, cur, elist);

    // ---- layer 1 ----
    mm_mfma_k<2, false><<<dim3(256, 2), thr, 0, stream>>>(
        x, x_SC, W1, W1s, We, Wes, dinv, A1h, A2h, S1, S2, nN);
    agg1_k<<<gNodeW, thr, 0, stream>>>(offs, elist, A1h, S1, b1, be, dinv, H11, nN);
    agg1_k<<<gNodeW, thr, 0, stream>>>(offs, elist, A2h, S2, b1s, bes, dinv, H12, nN);

    // ---- layer 2 ----
    mm_mfma_k<1, true><<<dim3(256, 2), thr, 0, stream>>>(
        H11, H12, W2, W2s, nullptr, nullptr, dinv, A1h, A2h, nullptr, nullptr, nN);
    agg2_dot_k<<<gNodeW, thr, 0, stream>>>(offs, elist, A1h, H11, b2, dinv, Wf, dot1, nN);
    agg2_dot_k<<<gNodeW, thr, 0, stream>>>(offs, elist, A2h, H12, b2s, dinv, Wf, dot2, nN);

    // ---- pool ----
    pool_reduce_k<<<nG, thr, 0, stream>>>(dot1, dot2, batch, nN, bf, (float*)d_out);
}

// Round 8
// 319.256 us; speedup vs baseline: 3.0460x; 1.1519x over previous
//
#include <hip/hip_runtime.h>
#include <stdint.h>

// GCN x2 layers x2 branches, N=50000, E=800000, C=64.
// Branch-interleaved f16 tables: [node][128] (ch 0-63 branch1, 64-127 branch2),
// 256 B/row. Gathers read one uint32/lane covering BOTH branches. MFMA matmuls
// (W in VGPRs, pitch-parametrized). Multi-block scan CSR build. Wf-dot fused
// into layer-2 agg; tiny pool reduce.

typedef _Float16 f16;
typedef _Float16 f16x2 __attribute__((ext_vector_type(2)));
typedef _Float16 f16x8 __attribute__((ext_vector_type(8)));
typedef float f32x4 __attribute__((ext_vector_type(4)));

// ---- degree histogram (doubles as CSR cursor after scanC rewrites it) ----
__global__ void deg_count_k(const int* __restrict__ dst, int nE, int* __restrict__ cnt) {
    int i = blockIdx.x * blockDim.x + threadIdx.x;
    if (i < nE) atomicAdd(&cnt[dst[i]], 1);
}

__global__ void dinv_k(const int* __restrict__ cnt, int n, float* __restrict__ dinv) {
    int i = blockIdx.x * blockDim.x + threadIdx.x;
    if (i < n) dinv[i] = 1.0f / sqrtf(1.0f + (float)cnt[i]);
}

// ---- 3-phase exclusive scan ----
__global__ __launch_bounds__(256) void scanA_k(const int* __restrict__ cnt, int n,
                                               int* __restrict__ offs, int* __restrict__ bsums) {
    int tid = threadIdx.x, lane = tid & 63, wid = tid >> 6;
    int base = blockIdx.x * 1024 + tid * 4;
    int v0 = (base + 0 < n) ? cnt[base + 0] : 0;
    int v1 = (base + 1 < n) ? cnt[base + 1] : 0;
    int v2 = (base + 2 < n) ? cnt[base + 2] : 0;
    int v3 = (base + 3 < n) ? cnt[base + 3] : 0;
    int lsum = v0 + v1 + v2 + v3;
    int s = lsum;
#pragma unroll
    for (int off = 1; off < 64; off <<= 1) {
        int t = __shfl_up(s, off);
        if (lane >= off) s += t;
    }
    __shared__ int wt[4];
    if (lane == 63) wt[wid] = s;
    __syncthreads();
    int woff = 0;
    for (int w = 0; w < wid; ++w) woff += wt[w];
    int excl = woff + s - lsum;
    if (base + 0 < n) offs[base + 0] = excl;
    if (base + 1 < n) offs[base + 1] = excl + v0;
    if (base + 2 < n) offs[base + 2] = excl + v0 + v1;
    if (base + 3 < n) offs[base + 3] = excl + v0 + v1 + v2;
    if (tid == 0) bsums[blockIdx.x] = wt[0] + wt[1] + wt[2] + wt[3];
}

__global__ void scanB_k(const int* __restrict__ bsums, int nb, int* __restrict__ boffs) {
    int lane = threadIdx.x;
    int carry = 0;
    for (int base = 0; base < nb; base += 64) {
        int i = base + lane;
        int v = (i < nb) ? bsums[i] : 0;
        int s = v;
#pragma unroll
        for (int off = 1; off < 64; off <<= 1) {
            int t = __shfl_up(s, off);
            if (lane >= off) s += t;
        }
        if (i < nb) boffs[i] = carry + s - v;
        carry += __shfl(s, 63);
    }
}

__global__ __launch_bounds__(256) void scanC_k(int* __restrict__ offs,
                                               const int* __restrict__ boffs,
                                               int* __restrict__ cur, int n, int nE) {
    int boff = boffs[blockIdx.x];
    int base = blockIdx.x * 1024 + threadIdx.x * 4;
#pragma unroll
    for (int j = 0; j < 4; ++j) {
        int i = base + j;
        if (i < n) {
            int o = offs[i] + boff;
            offs[i] = o;
            cur[i] = o;
        }
    }
    if (blockIdx.x == 0 && threadIdx.x == 0) offs[n] = nE;
}

__global__ void fill_k(const int* __restrict__ src, const int* __restrict__ dst, int nE,
                       int* __restrict__ cur, int* __restrict__ elist) {
    int e = blockIdx.x * blockDim.x + threadIdx.x;
    if (e < nE) {
        int p = atomicAdd(&cur[dst[e]], 1);
        elist[p] = src[e];
    }
}

// ---- MFMA matmul: per branch (blockIdx.y), Oa = f16(dinv*(X@Wa)),
//      and (NW==2) Oc = f16(X@Wc). One wave = 16-row x 64-col slab.
// Pitch-parametrized: X pitch xP (f32 or f16), outputs pitch oP with the
// branch column offset baked into the Oa/Oc pointers.
// 16x16x32 f16 layouts: A[row=l&15][k=(l>>4)*8+j]; B[k=(l>>4)*8+j][col=l&15];
// D[row=(l>>4)*4+j][col=l&15]  (m89-verified C/D mapping).
template <int NW, bool F16IN>
__global__ __launch_bounds__(256) void mm_mfma_k(
    const void* __restrict__ X1, const void* __restrict__ X2,
    const float* __restrict__ Wa1, const float* __restrict__ Wa2,
    const float* __restrict__ Wc1, const float* __restrict__ Wc2,
    const float* __restrict__ dinv,
    f16* __restrict__ Oa1, f16* __restrict__ Oa2,
    f16* __restrict__ Oc1, f16* __restrict__ Oc2,
    int xP, int oP, int n) {
    const int branch = blockIdx.y;
    const void* X   = branch ? X2 : X1;
    const float* Wa = branch ? Wa2 : Wa1;
    const float* Wc = branch ? Wc2 : Wc1;
    f16* Oa = branch ? Oa2 : Oa1;
    f16* Oc = branch ? Oc2 : Oc1;

    const int lane = threadIdx.x & 63;
    const int col = lane & 15;       // B/D column within 16-col tile
    const int kgrp = lane >> 4;      // 0..3

    // W fragments in VGPRs: [col-tile][k-half]
    f16x8 wa[4][2], wc[4][2];
#pragma unroll
    for (int ct = 0; ct < 4; ++ct)
#pragma unroll
        for (int kk = 0; kk < 2; ++kk) {
#pragma unroll
            for (int j = 0; j < 8; ++j) {
                int widx = (kk * 32 + kgrp * 8 + j) * 64 + ct * 16 + col;
                wa[ct][kk][j] = (f16)Wa[widx];
                if (NW == 2) wc[ct][kk][j] = (f16)Wc[widx];
            }
        }

    const int wid = blockIdx.x * 4 + (threadIdx.x >> 6);
    const int nwaves = gridDim.x * 4;
    const int ntiles = (n + 15) >> 4;
    for (int t = wid; t < ntiles; t += nwaves) {
        int arow = t * 16 + col;
        if (arow >= n) arow = n - 1;
        f16x8 af[2];
#pragma unroll
        for (int kk = 0; kk < 2; ++kk) {
            if (F16IN) {
                af[kk] = *(const f16x8*)((const f16*)X + (size_t)arow * xP + kk * 32 + kgrp * 8);
            } else {
                const float4* px = (const float4*)((const float*)X + (size_t)arow * xP + kk * 32 + kgrp * 8);
                float4 u0 = px[0], u1 = px[1];
                af[kk][0] = (f16)u0.x; af[kk][1] = (f16)u0.y;
                af[kk][2] = (f16)u0.z; af[kk][3] = (f16)u0.w;
                af[kk][4] = (f16)u1.x; af[kk][5] = (f16)u1.y;
                af[kk][6] = (f16)u1.z; af[kk][7] = (f16)u1.w;
            }
        }
        f32x4 acca[4], accc[4];
#pragma unroll
        for (int ct = 0; ct < 4; ++ct) {
            acca[ct] = (f32x4)(0.0f);
            if (NW == 2) accc[ct] = (f32x4)(0.0f);
        }
#pragma unroll
        for (int ct = 0; ct < 4; ++ct)
#pragma unroll
            for (int kk = 0; kk < 2; ++kk) {
                acca[ct] = __builtin_amdgcn_mfma_f32_16x16x32_f16(af[kk], wa[ct][kk], acca[ct], 0, 0, 0);
                if (NW == 2)
                    accc[ct] = __builtin_amdgcn_mfma_f32_16x16x32_f16(af[kk], wc[ct][kk], accc[ct], 0, 0, 0);
            }
        int rbase = t * 16 + kgrp * 4;
#pragma unroll
        for (int j = 0; j < 4; ++j) {
            int row = rbase + j;
            if (row < n) {
                float d = dinv[row];
#pragma unroll
                for (int ct = 0; ct < 4; ++ct) {
                    Oa[(size_t)row * oP + ct * 16 + col] = (f16)(d * acca[ct][j]);
                    if (NW == 2)
                        Oc[(size_t)row * oP + ct * 16 + col] = (f16)(accc[ct][j]);
                }
            }
        }
    }
}

// ---- layer-1 agg, BOTH branches in one pass over interleaved table ----
// Lane l covers combined channels {2l, 2l+1}: branch = l>=32, ch0 = 2l mod 64.
// H[node] = relu(dinv*(self + sum A[src]) + b) + relu(skip + bskip)  (interleaved f16 out)
__global__ __launch_bounds__(256) void agg1_k(
    const int* __restrict__ offs, const int* __restrict__ elist,
    const uint32_t* __restrict__ Aw, const uint32_t* __restrict__ Sw,
    const float* __restrict__ b1, const float* __restrict__ b1s,
    const float* __restrict__ be, const float* __restrict__ bes,
    const float* __restrict__ dinv, uint32_t* __restrict__ Hw, int n) {
    int node = blockIdx.x * 4 + (threadIdx.x >> 6);
    int lane = threadIdx.x & 63;
    if (node >= n) return;
    int br = lane >> 5;
    int ch0 = (lane & 31) * 2;
    float bb0 = br ? b1s[ch0] : b1[ch0];
    float bb1 = br ? b1s[ch0 + 1] : b1[ch0 + 1];
    float bs0 = br ? bes[ch0] : be[ch0];
    float bs1 = br ? bes[ch0 + 1] : be[ch0 + 1];

    int e0 = offs[node], e1 = offs[node + 1];
    f16x2 selfv = __builtin_bit_cast(f16x2, Aw[(size_t)node * 64 + lane]);
    float acc0 = (float)selfv.x, acc1 = (float)selfv.y;
    int e = e0;
    for (; e + 7 < e1; e += 8) {
        int s0 = elist[e], s1 = elist[e + 1], s2 = elist[e + 2], s3 = elist[e + 3];
        int s4 = elist[e + 4], s5 = elist[e + 5], s6 = elist[e + 6], s7 = elist[e + 7];
        f16x2 v0 = __builtin_bit_cast(f16x2, Aw[(size_t)s0 * 64 + lane]);
        f16x2 v1 = __builtin_bit_cast(f16x2, Aw[(size_t)s1 * 64 + lane]);
        f16x2 v2 = __builtin_bit_cast(f16x2, Aw[(size_t)s2 * 64 + lane]);
        f16x2 v3 = __builtin_bit_cast(f16x2, Aw[(size_t)s3 * 64 + lane]);
        f16x2 v4 = __builtin_bit_cast(f16x2, Aw[(size_t)s4 * 64 + lane]);
        f16x2 v5 = __builtin_bit_cast(f16x2, Aw[(size_t)s5 * 64 + lane]);
        f16x2 v6 = __builtin_bit_cast(f16x2, Aw[(size_t)s6 * 64 + lane]);
        f16x2 v7 = __builtin_bit_cast(f16x2, Aw[(size_t)s7 * 64 + lane]);
        acc0 += (((float)v0.x + (float)v1.x) + ((float)v2.x + (float)v3.x)) +
                (((float)v4.x + (float)v5.x) + ((float)v6.x + (float)v7.x));
        acc1 += (((float)v0.y + (float)v1.y) + ((float)v2.y + (float)v3.y)) +
                (((float)v4.y + (float)v5.y) + ((float)v6.y + (float)v7.y));
    }
    for (; e < e1; ++e) {
        f16x2 v = __builtin_bit_cast(f16x2, Aw[(size_t)elist[e] * 64 + lane]);
        acc0 += (float)v.x;
        acc1 += (float)v.y;
    }
    float d = dinv[node];
    float g0 = fmaxf(d * acc0 + bb0, 0.0f);
    float g1 = fmaxf(d * acc1 + bb1, 0.0f);
    f16x2 sv = __builtin_bit_cast(f16x2, Sw[(size_t)node * 64 + lane]);
    g0 += fmaxf((float)sv.x + bs0, 0.0f);
    g1 += fmaxf((float)sv.y + bs1, 0.0f);
    f16x2 o; o.x = (f16)g0; o.y = (f16)g1;
    Hw[(size_t)node * 64 + lane] = __builtin_bit_cast(uint32_t, o);
}

// ---- layer-2 agg + Wf dot, BOTH branches in one pass ----
// dot[node] = sum over all 128 combined channels of (relu(...)+H1)*Wf[ch]
__global__ __launch_bounds__(256) void agg2_dot_k(
    const int* __restrict__ offs, const int* __restrict__ elist,
    const uint32_t* __restrict__ Aw, const uint32_t* __restrict__ Hw,
    const float* __restrict__ b2, const float* __restrict__ b2s,
    const float* __restrict__ Wf, const float* __restrict__ dinv,
    float* __restrict__ dot, int n) {
    int node = blockIdx.x * 4 + (threadIdx.x >> 6);
    int lane = threadIdx.x & 63;
    if (node >= n) return;
    int br = lane >> 5;
    int ch0 = (lane & 31) * 2;
    float bb0 = br ? b2s[ch0] : b2[ch0];
    float bb1 = br ? b2s[ch0 + 1] : b2[ch0 + 1];
    float wf0 = Wf[ch0], wf1 = Wf[ch0 + 1];

    int e0 = offs[node], e1 = offs[node + 1];
    f16x2 selfv = __builtin_bit_cast(f16x2, Aw[(size_t)node * 64 + lane]);
    float acc0 = (float)selfv.x, acc1 = (float)selfv.y;
    int e = e0;
    for (; e + 7 < e1; e += 8) {
        int s0 = elist[e], s1 = elist[e + 1], s2 = elist[e + 2], s3 = elist[e + 3];
        int s4 = elist[e + 4], s5 = elist[e + 5], s6 = elist[e + 6], s7 = elist[e + 7];
        f16x2 v0 = __builtin_bit_cast(f16x2, Aw[(size_t)s0 * 64 + lane]);
        f16x2 v1 = __builtin_bit_cast(f16x2, Aw[(size_t)s1 * 64 + lane]);
        f16x2 v2 = __builtin_bit_cast(f16x2, Aw[(size_t)s2 * 64 + lane]);
        f16x2 v3 = __builtin_bit_cast(f16x2, Aw[(size_t)s3 * 64 + lane]);
        f16x2 v4 = __builtin_bit_cast(f16x2, Aw[(size_t)s4 * 64 + lane]);
        f16x2 v5 = __builtin_bit_cast(f16x2, Aw[(size_t)s5 * 64 + lane]);
        f16x2 v6 = __builtin_bit_cast(f16x2, Aw[(size_t)s6 * 64 + lane]);
        f16x2 v7 = __builtin_bit_cast(f16x2, Aw[(size_t)s7 * 64 + lane]);
        acc0 += (((float)v0.x + (float)v1.x) + ((float)v2.x + (float)v3.x)) +
                (((float)v4.x + (float)v5.x) + ((float)v6.x + (float)v7.x));
        acc1 += (((float)v0.y + (float)v1.y) + ((float)v2.y + (float)v3.y)) +
                (((float)v4.y + (float)v5.y) + ((float)v6.y + (float)v7.y));
    }
    for (; e < e1; ++e) {
        f16x2 v = __builtin_bit_cast(f16x2, Aw[(size_t)elist[e] * 64 + lane]);
        acc0 += (float)v.x;
        acc1 += (float)v.y;
    }
    float d = dinv[node];
    f16x2 hv = __builtin_bit_cast(f16x2, Hw[(size_t)node * 64 + lane]);
    float h0 = fmaxf(d * acc0 + bb0, 0.0f) + (float)hv.x;
    float h1 = fmaxf(d * acc1 + bb1, 0.0f) + (float)hv.y;
    float c = h0 * wf0 + h1 * wf1;
#pragma unroll
    for (int off = 32; off > 0; off >>= 1) c += __shfl_down(c, off);
    if (lane == 0) dot[node] = c;   // = (h2 + hs2) . Wf  for this node
}

// ---- pool: one block per graph over per-node dots (batch sorted) ----
__device__ inline int lower_bound(const int* __restrict__ batch, int n, int g) {
    int lo = 0, hi = n;
    while (lo < hi) {
        int mid = (lo + hi) >> 1;
        if (batch[mid] < g) lo = mid + 1; else hi = mid;
    }
    return lo;
}

__global__ __launch_bounds__(256) void pool_reduce_k(
    const float* __restrict__ dot, const int* __restrict__ batch, int n,
    const float* __restrict__ bf, float* __restrict__ out) {
    int g = blockIdx.x;
    int start = lower_bound(batch, n, g);
    int end = lower_bound(batch, n, g + 1);
    int tid = threadIdx.x, lane = tid & 63, wid = tid >> 6;
    float acc = 0.f;
    for (int i = start + tid; i < end; i += blockDim.x) acc += dot[i];
#pragma unroll
    for (int off = 32; off > 0; off >>= 1) acc += __shfl_down(acc, off);
    __shared__ float part[4];
    if (lane == 0) part[wid] = acc;
    __syncthreads();
    if (tid == 0) {
        float s = part[0] + part[1] + part[2] + part[3];
        float cnt = fmaxf((float)(end - start), 1.0f);
        out[g] = s / cnt + bf[0];
    }
}

static inline char* alignp(char* p, uintptr_t a) {
    return (char*)(((uintptr_t)p + a - 1) & ~(a - 1));
}

extern "C" void kernel_launch(void* const* d_in, const int* in_sizes, int n_in,
                              void* d_out, int out_size, void* d_ws, size_t ws_size,
                              hipStream_t stream) {
    const float* x    = (const float*)d_in[0];
    const float* x_SC = (const float*)d_in[1];
    const float* W1   = (const float*)d_in[2];
    const float* b1   = (const float*)d_in[3];
    const float* W2   = (const float*)d_in[4];
    const float* b2   = (const float*)d_in[5];
    const float* We   = (const float*)d_in[6];
    const float* be   = (const float*)d_in[7];
    const float* W1s  = (const float*)d_in[8];
    const float* b1s  = (const float*)d_in[9];
    const float* W2s  = (const float*)d_in[10];
    const float* b2s  = (const float*)d_in[11];
    const float* Wes  = (const float*)d_in[12];
    const float* bes  = (const float*)d_in[13];
    const float* Wf   = (const float*)d_in[14];
    const float* bf   = (const float*)d_in[15];
    const int* ei     = (const int*)d_in[16];
    const int* batch  = (const int*)d_in[17];

    const int nN = in_sizes[0] / 64;   // 50000
    const int nE = in_sizes[16] / 2;   // 800000
    const int nG = out_size;           // 64
    const int* esrc = ei;
    const int* edst = ei + nE;
    const int nb = (nN + 1023) / 1024;

    // ---- workspace (64B-aligned chunks) ----
    char* p = (char*)d_ws;
    int* cur    = (int*)p;   p = alignp(p + (size_t)nN * sizeof(int), 64);
    int* offs   = (int*)p;   p = alignp(p + (size_t)(nN + 1) * sizeof(int), 64);
    int* elist  = (int*)p;   p = alignp(p + (size_t)nE * sizeof(int), 64);
    int* bsums  = (int*)p;   p = alignp(p + 1024 * sizeof(int), 64);
    int* boffs  = (int*)p;   p = alignp(p + 1024 * sizeof(int), 64);
    float* dinv = (float*)p; p = alignp(p + (size_t)nN * sizeof(float), 64);
    float* dot  = (float*)p; p = alignp(p + (size_t)nN * sizeof(float), 64);
    f16* A = (f16*)p;        p = alignp(p + (size_t)nN * 128 * sizeof(f16), 64);  // interleaved
    f16* S = (f16*)p;        p = alignp(p + (size_t)nN * 128 * sizeof(f16), 64);  // interleaved skip
    f16* H = (f16*)p;        p = alignp(p + (size_t)nN * 128 * sizeof(f16), 64);  // interleaved H1

    const int thr = 256;
    const int gEdgeT = (nE + thr - 1) / thr;
    const int gNodeT = (nN + thr - 1) / thr;
    const int gNodeW = (nN + 3) / 4;   // 1 wave/node

    // ---- CSR build + dinv ----
    hipMemsetAsync(cur, 0, (size_t)nN * sizeof(int), stream);
    deg_count_k<<<gEdgeT, thr, 0, stream>>>(edst, nE, cur);
    dinv_k<<<gNodeT, thr, 0, stream>>>(cur, nN, dinv);
    scanA_k<<<nb, thr, 0, stream>>>(cur, nN, offs, bsums);
    scanB_k<<<1, 64, 0, stream>>>(bsums, nb, boffs);
    scanC_k<<<nb, thr, 0, stream>>>(offs, boffs, cur, nN, nE);
    fill_k<<<gEdgeT, thr, 0, stream>>>(esrc, edst, nE, cur, elist);

    // ---- layer 1: A[:,0:64]=f16(d*(x@W1)), A[:,64:128]=f16(d*(xsc@W1s)),
    //               S likewise with We/Wes (unscaled) ----
    mm_mfma_k<2, false><<<dim3(256, 2), thr, 0, stream>>>(
        x, x_SC, W1, W1s, We, Wes, dinv,
        A, A + 64, S, S + 64, 64, 128, nN);
    agg1_k<<<gNodeW, thr, 0, stream>>>(offs, elist, (const uint32_t*)A, (const uint32_t*)S,
                                       b1, b1s, be, bes, dinv, (uint32_t*)H, nN);

    // ---- layer 2: A = f16(d*(H@W2)) per branch (interleaved in/out) ----
    mm_mfma_k<1, true><<<dim3(256, 2), thr, 0, stream>>>(
        H, H + 64, W2, W2s, nullptr, nullptr, dinv,
        A, A + 64, nullptr, nullptr, 128, 128, nN);
    agg2_dot_k<<<gNodeW, thr, 0, stream>>>(offs, elist, (const uint32_t*)A, (const uint32_t*)H,
                                           b2, b2s, Wf, dinv, dot, nN);

    // ---- pool ----
    pool_reduce_k<<<nG, thr, 0, stream>>>(dot, batch, nN, bf, (float*)d_out);
}